// Round 1
// baseline (66.194 us; speedup 1.0000x reference)
//
#include <hip/hip_runtime.h>
#include <hip/hip_fp16.h>
#include <math.h>

#define N 512
#define BATCH 256
#define KTOP 16
#define NLAYERS 45
#define NPAIRS 256

typedef _Float16 half8 __attribute__((ext_vector_type(8)));
typedef _Float16 half4 __attribute__((ext_vector_type(4)));

// Cross-lane xor via DPP (VALU pipe, NOT the DS pipe):
//   xor1 = quad_perm[1,0,3,2] = 0xB1; xor2 = quad_perm[2,3,0,1] = 0x4E;
//   xor8 = row_ror:8 = 0x128. xor4 stays on __shfl_xor (DS);
//   xor16/xor32 now use v_permlane16/32_swap_b32 (gfx950, VALU pipe).
template<int CTRL>
__device__ __forceinline__ float dpp_xor(float x) {
    return __int_as_float(
        __builtin_amdgcn_mov_dpp(__float_as_int(x), CTRL, 0xF, 0xF, true));
}

// v_permlane16_swap_b32 vdst, vsrc: vdst odd 16-rows <-> vsrc even 16-rows.
// v_permlane32_swap_b32 vdst, vsrc: vdst hi 32-half  <-> vsrc lo 32-half.
__device__ __forceinline__ void plane16_swap(float& a, float& b) {
    asm("v_permlane16_swap_b32 %0, %1" : "+v"(a), "+v"(b));
}
__device__ __forceinline__ void plane32_swap(float& a, float& b) {
    asm("v_permlane32_swap_b32 %0, %1" : "+v"(a), "+v"(b));
}

// f16 alpha consumed directly: clang fuses fpext(f16) into v_fma_mix_f32.
__device__ __forceinline__ float fmah(_Float16 a, float b, float c) {
    return __builtin_fmaf((float)a, b, c);
}

// alpha = atan(t)/pi + 0.5 via minimax odd poly (deg 11) + rcp range
// reduction. |err| ~1e-7 in alpha; output threshold is 1.2e-2.
__device__ __forceinline__ float fast_alpha(float t) {
    const float at  = __builtin_fabsf(t);
    const bool inv  = at > 1.0f;
    const float z   = inv ? __builtin_amdgcn_rcpf(at) : at;
    const float s   = z * z;
    float p = -0.0117212f;
    p = __builtin_fmaf(p, s,  0.05265332f);
    p = __builtin_fmaf(p, s, -0.11643287f);
    p = __builtin_fmaf(p, s,  0.19354346f);
    p = __builtin_fmaf(p, s, -0.33262347f);
    p = __builtin_fmaf(p, s,  0.99997726f);
    float r = z * p;
    r = inv ? (1.5707963267948966f - r) : r;
    r = (t < 0.0f) ? -r : r;
    return __builtin_fmaf(r, 0.3183098861837907f, 0.5f);
}

// One 1024-thread block (16 waves) per batch element.
//
// Forward (waves 0-7): element i on lane (i&63) of wave (i>>6), in a
//   register. j in {1,2,8} -> DPP; j in {4,16,32} -> shfl; j in
//   {64,128,256} -> ping-pong LDS + barrier. Alphas -> As[t][ord] as f16
//   (halves the dominant LDS read traffic in backward; backward consumes
//   via v_fma_mix so no extra VALU).
//
// Backward (all 16 waves): out row kk = row (511-kk) of L45*...*L1*I;
//   ONE row per wave, element i at (lane=i>>3, slot=i&7).
//   lg in {3,4,6}: DPP partner fetch. lg==5 (lane-xor4): ds_swizzle.
//   lg in {7,8} (lane-xor 16/32): paired permlane swap — alpha is
//   pair-symmetric (al[l]==al[l^m]), so swap(A,B) leaves even rows with
//   both A-values and odd rows with both B-values; d=A-B, n0=fma(al,d,B),
//   n1=fma(al,-d,A), swap(n0,n1) -> (newA,newB). 6 instr / 2 regs, all
//   VALU, zero DS. lg<3 -> in-register slot pairs. Fully unrolled.
__global__ __launch_bounds__(1024, 1)
void difftopk_kernel(const float* __restrict__ x_in, float* __restrict__ out) {
    __shared__ float xs[2][N];
    __shared__ __align__(16) _Float16 As[NLAYERS][NPAIRS];

    const int b    = blockIdx.x;
    const int tid  = threadIdx.x;
    const int lane = tid & 63;

    // ---------------- forward (waves 0-7) ----------------
    if (tid < N) {
        const int e = tid;
        float o = x_in[(size_t)b * N + e];

        int t = 0, par = 0;
        #pragma unroll
        for (int s = 1; s <= 9; ++s) {
            const int k  = 1 << s;
            const bool kb = (e & k) == 0;
            #pragma unroll
            for (int lg = s - 1; lg >= 0; --lg, ++t) {
                const int j = 1 << lg;
                float p;
                if (lg >= 6) {              // cross-wave: LDS ping-pong
                    xs[par][e] = o;
                    __syncthreads();
                    p = xs[par][e ^ j];
                    par ^= 1;
                } else if (lg == 0) {
                    p = dpp_xor<0xB1>(o);
                } else if (lg == 1) {
                    p = dpp_xor<0x4E>(o);
                } else if (lg == 3) {
                    p = dpp_xor<0x128>(o);
                } else {                    // j in {4,16,32}
                    p = __shfl_xor(o, j, 64);
                }
                const bool jb = (e & j) == 0;
                const float d = (kb == jb) ? (p - o) : (o - p);   // c - a
                const float alpha = fast_alpha(d * 10.0f);
                o = __builtin_fmaf(alpha, o - p, p);
                if (jb) {
                    const int ord = ((e >> (lg + 1)) << lg) | (e & (j - 1));
                    As[t][ord] = (_Float16)alpha;
                }
            }
        }
        __syncthreads();   // publish all alphas (barrier #7)
    } else {
        // waves 8-15: match forward's 7 barriers (6 ping-pong + 1 publish)
        #pragma unroll 1
        for (int i = 0; i < 7; ++i) __syncthreads();
    }

    // ---------------- backward (all 16 waves, 1 row each) ----------------
    const int wave  = tid >> 6;        // 0..15 -> output row kk = wave
    const int lane8 = lane << 3;
    const int r     = N - 1 - wave;
    const bool lo16 = (lane & 16) == 0;
    const bool lo32 = (lane & 32) == 0;

    float v[8];
    #pragma unroll
    for (int m = 0; m < 8; ++m) v[m] = (lane8 + m == r) ? 1.0f : 0.0f;

    #pragma unroll
    for (int s = 9; s >= 1; --s) {
        const int base = (s * (s - 1)) >> 1;
        #pragma unroll
        for (int lg = 0; lg < s; ++lg) {
            const int tt = base + (s - 1 - lg);
            if (lg >= 3) {
                const int j    = 1 << lg;
                const int ordb = ((lane8 >> (lg + 1)) << lg) | (lane8 & (j - 1));
                const half8 alh = *(const half8*)&As[tt][ordb];  // 1x ds_read_b128
                if (lg == 7) {
                    // lane-xor16 via paired v_permlane16_swap_b32
                    #pragma unroll
                    for (int m = 0; m < 8; m += 2) {
                        float A = v[m], B = v[m + 1];
                        plane16_swap(A, B);
                        // even rows: (A_own, A_partner); odd rows: (B_partner, B_own)
                        const _Float16 ha = lo16 ? alh[m] : alh[m + 1];
                        const float d  = A - B;
                        float n0 = fmah(ha,  d, B);
                        float n1 = fmah(ha, -d, A);
                        plane16_swap(n0, n1);     // -> (newA, newB)
                        v[m] = n0; v[m + 1] = n1;
                    }
                } else if (lg == 8) {
                    // lane-xor32 via paired v_permlane32_swap_b32
                    #pragma unroll
                    for (int m = 0; m < 8; m += 2) {
                        float A = v[m], B = v[m + 1];
                        plane32_swap(A, B);
                        const _Float16 ha = lo32 ? alh[m] : alh[m + 1];
                        const float d  = A - B;
                        float n0 = fmah(ha,  d, B);
                        float n1 = fmah(ha, -d, A);
                        plane32_swap(n0, n1);
                        v[m] = n0; v[m + 1] = n1;
                    }
                } else {
                    #pragma unroll
                    for (int m = 0; m < 8; ++m) {
                        float p;
                        if (lg == 3)      p = dpp_xor<0xB1>(v[m]);
                        else if (lg == 4) p = dpp_xor<0x4E>(v[m]);
                        else if (lg == 6) p = dpp_xor<0x128>(v[m]);
                        else              p = __shfl_xor(v[m], 4, 64);  // lg==5
                        v[m] = fmah(alh[m], v[m] - p, p);
                    }
                }
            } else {
                const half4 a4 = *(const half4*)&As[tt][lane << 2];  // ds_read_b64
                if (lg == 2) {
                    #pragma unroll
                    for (int i = 0; i < 4; ++i) {
                        const float x0 = v[i], x1 = v[i + 4], d = x0 - x1;
                        v[i]     = fmah(a4[i],  d, x1);
                        v[i + 4] = fmah(a4[i], -d, x0);
                    }
                } else if (lg == 1) {
                    #pragma unroll
                    for (int i = 0; i < 4; ++i) {
                        const int lo = (((i >> 1) << 2) | (i & 1));
                        const float x0 = v[lo], x1 = v[lo + 2], d = x0 - x1;
                        v[lo]     = fmah(a4[i],  d, x1);
                        v[lo + 2] = fmah(a4[i], -d, x0);
                    }
                } else {
                    #pragma unroll
                    for (int i = 0; i < 4; ++i) {
                        const int lo = i << 1;
                        const float x0 = v[lo], x1 = v[lo + 1], d = x0 - x1;
                        v[lo]     = fmah(a4[i],  d, x1);
                        v[lo + 1] = fmah(a4[i], -d, x0);
                    }
                }
            }
        }
    }

    // ---------------- write out[b, wave, :] ----------------
    float4* dst = (float4*)(out + ((size_t)b * KTOP + wave) * N + lane8);
    dst[0] = make_float4(v[0], v[1], v[2], v[3]);
    dst[1] = make_float4(v[4], v[5], v[6], v[7]);
}

extern "C" void kernel_launch(void* const* d_in, const int* in_sizes, int n_in,
                              void* d_out, int out_size, void* d_ws, size_t ws_size,
                              hipStream_t stream) {
    const float* x = (const float*)d_in[0];
    float* out = (float*)d_out;
    difftopk_kernel<<<dim3(BATCH), dim3(1024), 0, stream>>>(x, out);
}